// Round 1
// baseline (540.895 us; speedup 1.0000x reference)
//
#include <hip/hip_runtime.h>
#include <math.h>

#define NSWEEP 10
#define NCHUNK 16   // n-chunks in max_outer (2048/16 = 128 rows per block)

__device__ __forceinline__ float dot4f(const float4 a, const float4 b) {
    return a.x * b.x + a.y * b.y + a.z * b.z + a.w * b.w;
}
__device__ __forceinline__ float4 rot4f(float c, const float4 a, float s, const float4 b) {
    float4 r;
    r.x = c * a.x + s * b.x;
    r.y = c * a.y + s * b.y;
    r.z = c * a.z + s * b.z;
    r.w = c * a.w + s * b.w;
    return r;
}
// monotone float<->uint map so unsigned atomicMax == float max (handles negatives)
__device__ __forceinline__ unsigned mapf(float v) {
    unsigned u = __float_as_uint(v);
    return (u & 0x80000000u) ? ~u : (u | 0x80000000u);
}
__device__ __forceinline__ float unmapf(unsigned u) {
    return __uint_as_float((u & 0x80000000u) ? (u ^ 0x80000000u) : ~u);
}

// ws[0..65535] <- map(-inf)
__global__ __launch_bounds__(256) void init_ws(unsigned* __restrict__ wsu) {
    wsu[blockIdx.x * 256 + threadIdx.x] = 0x007FFFFFu;  // map of 0xFF800000 (-inf)
}

// M[b][i][j] = max_n x[b,n,i]*x[b,n,j]; grid = (NCHUNK, 16), block = 256
__global__ __launch_bounds__(256) void max_outer(const float* __restrict__ x,
                                                 unsigned* __restrict__ wsu) {
    __shared__ __align__(16) float xs[32 * 64];
    const int b = blockIdx.y;
    const int n0 = blockIdx.x * (2048 / NCHUNK);
    const int t = threadIdx.x;
    const int ti = t >> 4, tj = t & 15;       // 16x16 grid of 4x4 tiles
    const int i0 = ti * 4, j0 = tj * 4;
    float m[4][4];
#pragma unroll
    for (int a = 0; a < 4; ++a)
#pragma unroll
        for (int c = 0; c < 4; ++c) m[a][c] = -3.402823466e38f;

    const int row = t >> 3, col8 = t & 7;     // staging map: 32 rows x 8 float-octs
    for (int sub = 0; sub < (2048 / NCHUNK) / 32; ++sub) {
        const float4* src4 =
            (const float4*)(x + (size_t)(b * 2048 + n0 + sub * 32 + row) * 64) + col8 * 2;
        float4* dst4 = (float4*)(xs + row * 64) + col8 * 2;
        dst4[0] = src4[0];
        dst4[1] = src4[1];
        __syncthreads();
#pragma unroll 8
        for (int rr = 0; rr < 32; ++rr) {
            const float4 av = ((const float4*)(xs + rr * 64))[ti];  // broadcast read
            const float4 bv = ((const float4*)(xs + rr * 64))[tj];  // stride-1 read
            const float aa[4] = {av.x, av.y, av.z, av.w};
            const float bb[4] = {bv.x, bv.y, bv.z, bv.w};
#pragma unroll
            for (int a = 0; a < 4; ++a)
#pragma unroll
                for (int c = 0; c < 4; ++c) m[a][c] = fmaxf(m[a][c], aa[a] * bb[c]);
        }
        __syncthreads();
    }
    unsigned* cell = wsu + b * 4096;
#pragma unroll
    for (int a = 0; a < 4; ++a)
#pragma unroll
        for (int c = 0; c < 4; ++c)
            atomicMax(cell + (i0 + a) * 64 + (j0 + c), mapf(m[a][c]));
}

// One-sided Jacobi SVD of symmetric M, then F = sum_k sign(rho_k) sqrt(|rho_k|) u_k u_k^T,
// Frobenius-normalized. grid = 16 (one block per batch), block = 256.
__global__ __launch_bounds__(256) void jacobi_sqrt(const unsigned* __restrict__ wsu,
                                                   float* __restrict__ out) {
    __shared__ __align__(16) float A[64 * 68];  // original M (stride 68), later U-transpose
    __shared__ __align__(16) float W[64 * 68];  // rows = columns being orthogonalized
    __shared__ __align__(16) float gvals[64];
    __shared__ float red[4];
    const int b = blockIdx.x;
    const int t = threadIdx.x;

    // load + unmap M into A and W
    for (int c = 0; c < 16; ++c) {
        int idx = c * 256 + t;
        int i = idx >> 6, j = idx & 63;
        float v = unmapf(wsu[b * 4096 + idx]);
        A[i * 68 + j] = v;
        W[i * 68 + j] = v;
    }
    __syncthreads();

    // ---- one-sided Jacobi: NSWEEP sweeps x 63 rounds x 32 disjoint pairs ----
    const int k = t >> 3, s8 = t & 7;  // pair id (0..31), 8-elem segment (0..7)
    for (int sweep = 0; sweep < NSWEEP; ++sweep) {
        for (int r = 0; r < 63; ++r) {
            int p, q;
            if (k == 0) {
                p = 63; q = r;
            } else {
                p = r + k; if (p >= 63) p -= 63;
                q = r - k; if (q < 0) q += 63;
            }
            float4* Wp = (float4*)(W + p * 68);
            float4* Wq = (float4*)(W + q * 68);
            const float4 p0 = Wp[s8 * 2], p1 = Wp[s8 * 2 + 1];
            const float4 q0 = Wq[s8 * 2], q1 = Wq[s8 * 2 + 1];
            float aa = dot4f(p0, p0) + dot4f(p1, p1);
            float bb = dot4f(q0, q0) + dot4f(q1, q1);
            float gg = dot4f(p0, q0) + dot4f(p1, q1);
            // 8-lane butterfly reduce (in-wave, no barrier)
            aa += __shfl_xor(aa, 1); bb += __shfl_xor(bb, 1); gg += __shfl_xor(gg, 1);
            aa += __shfl_xor(aa, 2); bb += __shfl_xor(bb, 2); gg += __shfl_xor(gg, 2);
            aa += __shfl_xor(aa, 4); bb += __shfl_xor(bb, 4); gg += __shfl_xor(gg, 4);
            float cc = 1.0f, ss = 0.0f;
            if (fabsf(gg) > 1e-20f) {
                float tau = (bb - aa) / (2.0f * gg);
                float tt = (tau >= 0.0f ? 1.0f : -1.0f) / (fabsf(tau) + sqrtf(1.0f + tau * tau));
                cc = 1.0f / sqrtf(1.0f + tt * tt);
                ss = tt * cc;
            }
            Wp[s8 * 2]     = rot4f(cc, p0, -ss, q0);
            Wp[s8 * 2 + 1] = rot4f(cc, p1, -ss, q1);
            Wq[s8 * 2]     = rot4f(ss, p0, cc, q0);
            Wq[s8 * 2 + 1] = rot4f(ss, p1, cc, q1);
            __syncthreads();  // single barrier per round (pairs touch disjoint rows)
        }
    }

    // ---- normalize rows of W -> U^T (4 lanes per vector k) ----
    const int kk = t >> 2, part = t & 3;
    {
        float4* Wk = (float4*)(W + kk * 68);
        float4 seg[4];
        float nrm = 0.0f;
#pragma unroll
        for (int c = 0; c < 4; ++c) {
            seg[c] = Wk[part * 4 + c];
            nrm += dot4f(seg[c], seg[c]);
        }
        nrm += __shfl_xor(nrm, 1);
        nrm += __shfl_xor(nrm, 2);
        float inv = rsqrtf(fmaxf(nrm, 1e-30f));
#pragma unroll
        for (int c = 0; c < 4; ++c) {
            float4 v = seg[c];
            v.x *= inv; v.y *= inv; v.z *= inv; v.w *= inv;
            Wk[part * 4 + c] = v;
        }
    }
    __syncthreads();

    // ---- signed eigenvalues via Rayleigh quotient rho_k = u_k^T A u_k ----
    {
        float4 uk[16];
        const float4* Wk = (const float4*)(W + kk * 68);
#pragma unroll
        for (int c = 0; c < 16; ++c) uk[c] = Wk[c];
        float rho = 0.0f;
        for (int ii = 0; ii < 16; ++ii) {
            int i = part * 16 + ii;
            const float4* Ai = (const float4*)(A + i * 68);
            float acc = 0.0f;
#pragma unroll
            for (int c = 0; c < 16; ++c) acc += dot4f(Ai[c], uk[c]);
            rho += W[kk * 68 + i] * acc;
        }
        rho += __shfl_xor(rho, 1);
        rho += __shfl_xor(rho, 2);
        if (part == 0) gvals[kk] = (rho >= 0.0f) ? sqrtf(rho) : -sqrtf(-rho);
    }
    __syncthreads();

    // ---- transpose: A[i][k] <- W[k][i]  (A no longer needed) ----
    {
        const int i = t & 63, kbase = (t >> 6) * 16;
        for (int c = 0; c < 16; ++c) {
            int kx = kbase + c;
            A[i * 68 + kx] = W[kx * 68 + i];
        }
    }
    __syncthreads();

    // ---- F[i][j] = sum_k g_k U[i][k] U[j][k]; Frobenius-normalize; store ----
    {
        const int fi = t >> 2, fj0 = (t & 3) * 16;
        const float4* g4 = (const float4*)gvals;
        const float4* Ui = (const float4*)(A + fi * 68);
        float4 ga[16];
#pragma unroll
        for (int c = 0; c < 16; ++c) {
            float4 gv = g4[c], uv = Ui[c];
            float4 rr;
            rr.x = gv.x * uv.x; rr.y = gv.y * uv.y; rr.z = gv.z * uv.z; rr.w = gv.w * uv.w;
            ga[c] = rr;
        }
        float fv[16];
        float sq = 0.0f;
        for (int jj = 0; jj < 16; ++jj) {
            const float4* Uj = (const float4*)(A + (fj0 + jj) * 68);
            float acc = 0.0f;
#pragma unroll
            for (int c = 0; c < 16; ++c) acc += dot4f(ga[c], Uj[c]);
            fv[jj] = acc;
            sq += acc * acc;
        }
#pragma unroll
        for (int d = 1; d < 64; d <<= 1) sq += __shfl_xor(sq, d);
        if ((t & 63) == 0) red[t >> 6] = sq;
        __syncthreads();
        float tot = red[0] + red[1] + red[2] + red[3];
        float scale = 1.0f / fmaxf(sqrtf(tot), 1e-12f);
        float4* o4 = (float4*)(out + (size_t)b * 4096 + fi * 64 + fj0);
#pragma unroll
        for (int c = 0; c < 4; ++c) {
            float4 v;
            v.x = fv[c * 4 + 0] * scale;
            v.y = fv[c * 4 + 1] * scale;
            v.z = fv[c * 4 + 2] * scale;
            v.w = fv[c * 4 + 3] * scale;
            o4[c] = v;
        }
    }
}

extern "C" void kernel_launch(void* const* d_in, const int* in_sizes, int n_in,
                              void* d_out, int out_size, void* d_ws, size_t ws_size,
                              hipStream_t stream) {
    const float* x = (const float*)d_in[0];   // [16,1,2048,64] fp32
    float* out = (float*)d_out;               // [16,4096] fp32
    unsigned* wsu = (unsigned*)d_ws;          // 65536 u32 = 256 KiB

    hipLaunchKernelGGL(init_ws, dim3(256), dim3(256), 0, stream, wsu);
    hipLaunchKernelGGL(max_outer, dim3(NCHUNK, 16), dim3(256), 0, stream, x, wsu);
    hipLaunchKernelGGL(jacobi_sqrt, dim3(16), dim3(256), 0, stream, wsu, out);
}